// Round 1
// baseline (274.192 us; speedup 1.0000x reference)
//
#include <hip/hip_runtime.h>
#include <math.h>

// Problem constants (B,T,D) = (32, 2048, 512), fp32.
constexpr int B = 32;
constexpr int T = 2048;
constexpr int D = 512;

// ---------------- zero init: s[B*D] and out[B*D] ----------------
__global__ void zero_kernel(float* __restrict__ s, float* __restrict__ out) {
    int i = blockIdx.x * blockDim.x + threadIdx.x;
    if (i < B * D) { s[i] = 0.0f; out[i] = 0.0f; }
}

// ---------------- pass 1: s[b,d] = sum_t x[b,t,d] ----------------
// grid (B, TCH), block 128; each thread owns one float4 column group,
// loops 32 rows, atomicAdd partial into s.
constexpr int TCH = 64;               // chunks over T
constexpr int TROWS = T / TCH;        // 32 rows per block

__global__ __launch_bounds__(128) void colsum_kernel(const float* __restrict__ x,
                                                     float* __restrict__ s) {
    const int b = blockIdx.x;
    const int chunk = blockIdx.y;
    const int d4 = threadIdx.x;                 // 0..127 -> d = 4*d4
    const float4* xrow = (const float4*)(x + (size_t)b * T * D + (size_t)chunk * TROWS * D) + d4;
    float4 acc = make_float4(0.f, 0.f, 0.f, 0.f);
    #pragma unroll 4
    for (int i = 0; i < TROWS; ++i) {
        float4 v = xrow[i * (D / 4)];
        acc.x += v.x; acc.y += v.y; acc.z += v.z; acc.w += v.w;
    }
    float* sp = s + b * D + 4 * d4;
    atomicAdd(sp + 0, acc.x);
    atomicAdd(sp + 1, acc.y);
    atomicAdd(sp + 2, acc.z);
    atomicAdd(sp + 3, acc.w);
}

// ---------------- pass 2: w[b,t] = x_bt . (s_b - x_bt) ----------------
// One wave (64 lanes) per row; lane covers 8 contiguous floats.
__global__ __launch_bounds__(256) void rowdot_kernel(const float* __restrict__ x,
                                                     const float* __restrict__ s,
                                                     float* __restrict__ w) {
    const int wid = threadIdx.x >> 6;           // wave in block (0..3)
    const int lane = threadIdx.x & 63;
    const int row = blockIdx.x * 4 + wid;       // global row in [0, B*T)
    const int b = row / T;
    const float4* xp = (const float4*)(x + (size_t)row * D) + lane * 2;
    const float4* sp = (const float4*)(s + (size_t)b * D) + lane * 2;
    float4 x0 = xp[0], x1 = xp[1];
    float4 s0 = sp[0], s1 = sp[1];
    double acc = 0.0;
    acc += (double)x0.x * (double)(s0.x - x0.x);
    acc += (double)x0.y * (double)(s0.y - x0.y);
    acc += (double)x0.z * (double)(s0.z - x0.z);
    acc += (double)x0.w * (double)(s0.w - x0.w);
    acc += (double)x1.x * (double)(s1.x - x1.x);
    acc += (double)x1.y * (double)(s1.y - x1.y);
    acc += (double)x1.z * (double)(s1.z - x1.z);
    acc += (double)x1.w * (double)(s1.w - x1.w);
    #pragma unroll
    for (int off = 32; off > 0; off >>= 1)
        acc += __shfl_down(acc, off, 64);
    if (lane == 0) w[row] = (float)acc;
}

// ---------------- pass 3: softmax over T, in place ----------------
__device__ __forceinline__ float block_reduce_max(float v) {
    __shared__ float sm[4];
    #pragma unroll
    for (int off = 32; off > 0; off >>= 1) v = fmaxf(v, __shfl_down(v, off, 64));
    if ((threadIdx.x & 63) == 0) sm[threadIdx.x >> 6] = v;
    __syncthreads();
    float r = fmaxf(fmaxf(sm[0], sm[1]), fmaxf(sm[2], sm[3]));
    __syncthreads();
    return r;
}
__device__ __forceinline__ float block_reduce_sum(float v) {
    __shared__ float ss[4];
    #pragma unroll
    for (int off = 32; off > 0; off >>= 1) v += __shfl_down(v, off, 64);
    if ((threadIdx.x & 63) == 0) ss[threadIdx.x >> 6] = v;
    __syncthreads();
    float r = ss[0] + ss[1] + ss[2] + ss[3];
    __syncthreads();
    return r;
}

__global__ __launch_bounds__(256) void softmax_kernel(float* __restrict__ w) {
    const int b = blockIdx.x;
    float* wb = w + (size_t)b * T;
    float vals[T / 256];
    float m = -INFINITY;
    #pragma unroll
    for (int i = 0; i < T / 256; ++i) {
        vals[i] = wb[threadIdx.x + i * 256];
        m = fmaxf(m, vals[i]);
    }
    const float M = block_reduce_max(m);
    float lsum = 0.f;
    #pragma unroll
    for (int i = 0; i < T / 256; ++i) {
        vals[i] = __expf(vals[i] - M);
        lsum += vals[i];
    }
    const float S = block_reduce_sum(lsum);
    const float inv = 1.0f / S;
    #pragma unroll
    for (int i = 0; i < T / 256; ++i)
        wb[threadIdx.x + i * 256] = vals[i] * inv;
}

// ---------------- pass 4: out[b,d] = sum_t weight[b,t] * x[b,t,d] ----------------
__global__ __launch_bounds__(128) void pool_kernel(const float* __restrict__ x,
                                                   const float* __restrict__ w,
                                                   float* __restrict__ out) {
    const int b = blockIdx.x;
    const int chunk = blockIdx.y;
    const int d4 = threadIdx.x;
    const int t0 = chunk * TROWS;
    const float4* xrow = (const float4*)(x + (size_t)b * T * D + (size_t)t0 * D) + d4;
    const float* wb = w + (size_t)b * T + t0;
    float4 acc = make_float4(0.f, 0.f, 0.f, 0.f);
    #pragma unroll 4
    for (int i = 0; i < TROWS; ++i) {
        float wt = wb[i];
        float4 v = xrow[i * (D / 4)];
        acc.x += wt * v.x; acc.y += wt * v.y; acc.z += wt * v.z; acc.w += wt * v.w;
    }
    float* op = out + b * D + 4 * d4;
    atomicAdd(op + 0, acc.x);
    atomicAdd(op + 1, acc.y);
    atomicAdd(op + 2, acc.z);
    atomicAdd(op + 3, acc.w);
}

extern "C" void kernel_launch(void* const* d_in, const int* in_sizes, int n_in,
                              void* d_out, int out_size, void* d_ws, size_t ws_size,
                              hipStream_t stream) {
    const float* x = (const float*)d_in[0];
    float* out = (float*)d_out;
    float* s = (float*)d_ws;                                   // B*D floats (64 KB)
    float* w = (float*)((char*)d_ws + (size_t)B * D * sizeof(float)); // B*T floats (256 KB)

    zero_kernel<<<(B * D + 255) / 256, 256, 0, stream>>>(s, out);
    colsum_kernel<<<dim3(B, TCH), 128, 0, stream>>>(x, s);
    rowdot_kernel<<<B * T / 4, 256, 0, stream>>>(x, s, w);
    softmax_kernel<<<B, 256, 0, stream>>>(w);
    pool_kernel<<<dim3(B, TCH), 128, 0, stream>>>(x, w, out);
}